// Round 7
// baseline (42.568 us; speedup 1.0000x reference)
//
#include <hip/hip_runtime.h>

#define D   256
#define NB  128
#define NV  53
#define NR  8192            // rows per side (64*128)
#define NG  28              // u-groups of 4 per side (112 u-slots)
#define SLB (NG*NR*4)       // 917504 ushorts per raw side-slice
#define ESOFF (2*SLB)       // E slices: PE @2*SLB, ME @3*SLB
#define WBOFF (4*SLB)       // fragment-ordered W (3584*8 ushorts)
#define BTOFF (WBOFF + 3584*8)  // bias table (112 floats)
#define LOG2E 1.44269504088896340736f
#define LN2   0.69314718055994530942f

// u-index: 0..52 = sub classes, 53..55 pad, 56..108 = ins classes (u-56), 109..111 pad.
// ws (ushort units): Praw@0, Mraw@SLB, PE@2*SLB, ME@3*SLB, WBg@WBOFF, biasT@BTOFF.
// slice element (u,row) at (u>>2)*NR*4 + row*4 + (u&3); raw = bf16(logit*log2e,
// bias folded into modern side); E = bf16(exp2(raw)), pads forced to 0.

typedef float  f4 __attribute__((ext_vector_type(4)));
typedef float  f2 __attribute__((ext_vector_type(2)));
typedef short  s8 __attribute__((ext_vector_type(8)));

__device__ __forceinline__ ushort f2bf(float f) {            // RNE f32 -> bf16
    uint u = __float_as_uint(f);
    u += 0x7fff + ((u >> 16) & 1);
    return (ushort)(u >> 16);
}
__device__ __forceinline__ float bflo(uint w) { return __uint_as_float(w << 16); }
__device__ __forceinline__ float bfhi(uint w) { return __uint_as_float(w & 0xffff0000u); }
__device__ __forceinline__ float fexp2(float x) { return __builtin_exp2f(x); }
__device__ __forceinline__ float flog2(float x) { return __builtin_log2f(x); }

// ---- p0: W -> u-indexed fragment-ordered bf16 (scaled by log2e) + bias table ----
__global__ void p0_kernel(const float* __restrict__ Wsub, const float* __restrict__ Wins,
                          const float* __restrict__ bsub, const float* __restrict__ bins,
                          ushort* __restrict__ WBg, float* __restrict__ biasT)
{
    const int F  = blockIdx.x * 64 + threadIdx.x;   // fragment slot 0..3583
    const int l  = F & 63, s = (F >> 6) & 7, nt = F >> 9;
    const int u  = nt * 16 + (l & 15);
    const int d0 = 32 * s + 8 * (l >> 4);
    const float* w = nullptr;
    if (u < NV)                  w = Wsub + u * D + d0;
    else if (u >= 56 && u <= 108) w = Wins + (u - 56) * D + d0;
    s8 bfr;
    if (w) {
        #pragma unroll
        for (int j = 0; j < 8; ++j) bfr[j] = (short)f2bf(w[j] * LOG2E);
    } else {
        #pragma unroll
        for (int j = 0; j < 8; ++j) bfr[j] = 0;
    }
    *(s8*)&WBg[F * 8] = bfr;
    if (F < 112) {
        float bv = 0.f;
        if (F < NV)                  bv = bsub[F] * LOG2E;
        else if (F >= 56 && F <= 108) bv = bins[F - 56] * LOG2E;
        biasT[F] = bv;
    }
}

// ---- p1: swapped-operand MFMA GEMM; 1 wave/block; W streamed from L2 ----
template<int NT0, int NNT>
__device__ __forceinline__ void p1_body(
    const float* __restrict__ prior, const float* __restrict__ modern,
    const ushort* __restrict__ WBg, const float* __restrict__ biasT,
    ushort* __restrict__ wsb, int lane, int tile)
{
    const int side = tile >> 9;                      // 0: prior, 1: modern
    const int row0 = (tile & 511) << 4;
    const int lrow = lane & 15, lk = lane >> 4;
    const float* __restrict__ src =
        (side ? modern : prior) + (size_t)(row0 + lrow) * D + lk * 8;

    f4 acc[NNT];
    #pragma unroll
    for (int j = 0; j < NNT; ++j) { acc[j][0]=0.f; acc[j][1]=0.f; acc[j][2]=0.f; acc[j][3]=0.f; }

    #pragma unroll
    for (int s = 0; s < 8; ++s) {
        const f4 c0 = *(const f4*)(src + 32 * s);
        const f4 c1 = *(const f4*)(src + 32 * s + 4);
        s8 a;
        a[0]=(short)f2bf(c0[0]); a[1]=(short)f2bf(c0[1]);
        a[2]=(short)f2bf(c0[2]); a[3]=(short)f2bf(c0[3]);
        a[4]=(short)f2bf(c1[0]); a[5]=(short)f2bf(c1[1]);
        a[6]=(short)f2bf(c1[2]); a[7]=(short)f2bf(c1[3]);
        #pragma unroll
        for (int j = 0; j < NNT; ++j) {
            const s8 wf = *(const s8*)&WBg[((((NT0 + j) << 3) + s) * 64 + lane) * 8];
            // A = W (M-dim = u), B = ctx (N-dim = row): D row = u, col = ctx row
            acc[j] = __builtin_amdgcn_mfma_f32_16x16x32_bf16(wf, a, acc[j], 0, 0, 0);
        }
    }

    // epilogue: lane holds u-quad {u0..u0+3} for ctx row (row0+lrow); 8-B stores
    ushort* __restrict__ raw = wsb + (size_t)side * SLB;
    ushort* __restrict__ Eb  = raw + ESOFF;
    const int row = row0 + lrow;
    #pragma unroll
    for (int j = 0; j < NNT; ++j) {
        const int u0 = (NT0 + j) * 16 + 4 * lk;
        f4 bias;
        if (side) bias = *(const f4*)&biasT[u0];
        else      { bias[0]=0.f; bias[1]=0.f; bias[2]=0.f; bias[3]=0.f; }
        ushort rq[4], eq[4];
        #pragma unroll
        for (int r = 0; r < 4; ++r) {
            const int u = u0 + r;
            const float val = acc[j][r] + bias[r];
            rq[r] = f2bf(val);
            const bool pad = (u > 52 && u < 56) || (u > 108);
            eq[r] = pad ? (ushort)0 : f2bf(fexp2(val));
        }
        const int addr = (u0 >> 2) * (NR * 4) + row * 4;
        *(uint2*)&raw[addr] = *(uint2*)rq;
        *(uint2*)&Eb[addr]  = *(uint2*)eq;
    }
}

__global__ __launch_bounds__(64) void p1_kernel(
    const float* __restrict__ prior, const float* __restrict__ modern,
    const ushort* __restrict__ WBg, const float* __restrict__ biasT,
    ushort* __restrict__ wsb)
{
    const int lane  = threadIdx.x;
    const int chunk = blockIdx.x & 3;     // nt chunks {0,1},{2,3},{4,5},{6}
    const int tile  = blockIdx.x >> 2;    // 0..1023
    if (chunk == 0)      p1_body<0, 2>(prior, modern, WBg, biasT, wsb, lane, tile);
    else if (chunk == 1) p1_body<2, 2>(prior, modern, WBg, biasT, wsb, lane, tile);
    else if (chunk == 2) p1_body<4, 2>(prior, modern, WBg, biasT, wsb, lane, tile);
    else                 p1_body<6, 1>(prior, modern, WBg, biasT, wsb, lane, tile);
}

// ---- p2: S = dot(EP,EM) over 14 u-groups per dist; lse = log2 S ----
__global__ __launch_bounds__(256) void p2_kernel(
    const ushort* __restrict__ wsb,
    const int* __restrict__ target, const int* __restrict__ srclen,
    const int* __restrict__ tgtlen, float* __restrict__ out)
{
    const int tid = threadIdx.x;
    const int b   = tid & 127;
    const int bid = blockIdx.x;
    const int xt  = ((bid & 7) << 2) | ((bid >> 3) & 3);   // 0..31 (XCD-banded x)
    const int y   = ((bid >> 5) << 1) | (tid >> 7);        // 0..63
    const int yb  = y * NB + b;

    const int sl = srclen[b], tl = tgtlen[b];
    const bool ymask = y < tl;
    const bool hasT  = y < 63;
    const int  t     = hasT ? target[y * NB + b] : 0;

    const ushort* __restrict__ Praw = wsb;
    const ushort* __restrict__ Mraw = wsb + SLB;
    const ushort* __restrict__ PE   = wsb + 2 * SLB;
    const ushort* __restrict__ ME   = wsb + 3 * SLB;

    #pragma unroll 1
    for (int dist = 0; dist < 2; ++dist) {                 // 0: sub, 1: ins
        const int g0   = dist * 14;
        const int tbase = (g0 + (t >> 2)) * (NR * 4) + (t & 3);
        const int a52b  = (g0 + 13) * (NR * 4);

        f2 em0[14], em1[14];
        #pragma unroll
        for (int g = 0; g < 14; ++g) {
            const uint2 q = *(const uint2*)(ME + ((g0 + g) * NR + yb) * 4);
            em0[g][0] = bflo(q.x); em0[g][1] = bfhi(q.x);
            em1[g][0] = bflo(q.y); em1[g][1] = bfhi(q.y);
        }
        const float mlt = bflo((uint)Mraw[tbase + yb * 4]);
        const float m52 = bflo((uint)Mraw[a52b  + yb * 4]);

        float* __restrict__ o0 = out + dist * 524288;              // del / end
        float* __restrict__ o1 = out + 1048576 + dist * 516096;    // sub_probs / ins_probs

        #pragma unroll
        for (int xi = 0; xi < 2; ++xi) {
            const int x  = xt * 2 + xi;
            const int xb = x * NB + b;
            const bool msk = (x < sl) & ymask;

            f2 s0; s0[0] = 0.f; s0[1] = 0.f;
            f2 s1; s1[0] = 0.f; s1[1] = 0.f;
            #pragma unroll
            for (int g = 0; g < 14; ++g) {
                const uint2 p = *(const uint2*)(PE + ((g0 + g) * NR + xb) * 4);
                f2 a; a[0] = bflo(p.x); a[1] = bfhi(p.x);
                f2 c; c[0] = bflo(p.y); c[1] = bfhi(p.y);
                s0 += a * em0[g];
                s1 += c * em1[g];
            }
            const float S  = (s0[0] + s0[1]) + (s1[0] + s1[1]);
            const float ls = flog2(S);

            const float l52 = bflo((uint)Praw[a52b + xb * 4]) + m52;
            o0[((x << 6) | y) * NB + b] = msk ? (l52 - ls) * LN2 : 0.f;
            if (hasT) {
                const float lt = bflo((uint)Praw[tbase + xb * 4]) + mlt;
                o1[(x * 63 + y) * NB + b] = msk ? (lt - ls) * LN2 : 0.f;
            }
        }
    }
}

extern "C" void kernel_launch(void* const* d_in, const int* in_sizes, int n_in,
                              void* d_out, int out_size, void* d_ws, size_t ws_size,
                              hipStream_t stream) {
    const float* prior  = (const float*)d_in[0];
    const float* modern = (const float*)d_in[1];
    const float* Wsub   = (const float*)d_in[2];
    const float* bsub   = (const float*)d_in[3];
    const float* Wins   = (const float*)d_in[4];
    const float* bins   = (const float*)d_in[5];
    const int*   target = (const int*)d_in[6];
    const int*   srclen = (const int*)d_in[7];
    const int*   tgtlen = (const int*)d_in[8];
    ushort* wsb   = (ushort*)d_ws;
    ushort* WBg   = wsb + WBOFF;
    float*  biasT = (float*)(wsb + BTOFF);
    float*  out   = (float*)d_out;

    p0_kernel<<<56, 64, 0, stream>>>(Wsub, Wins, bsub, bins, WBg, biasT);
    // p1: 1024 tiles x 4 nt-chunks, 1 wave/block -> 16 waves/CU (4/SIMD)
    p1_kernel<<<4096, 64, 0, stream>>>(prior, modern, WBg, biasT, wsb);
    // p2: 32 x-tiles (XT=2) x 32 y-pairs -> 1024 blocks (4/SIMD)
    p2_kernel<<<1024, 256, 0, stream>>>(wsb, target, srclen, tgtlen, out);
}

// Round 8
// 39.230 us; speedup vs baseline: 1.0851x; 1.0851x over previous
//
#include <hip/hip_runtime.h>

#define D   256
#define NB  128
#define NV  53
#define NR  8192            // rows per side (64*128)
#define V4  14              // v-groups of 4 (56 slots)
#define SLB (V4*NR*4)       // 458752 ushorts per slice
#define WBOFF (4*SLB)       // fragment-ordered W (3584*8 ushorts)
#define BTOFF (WBOFF + 3584*8)  // bias table (112 floats)

// ws (ushort units): PS @0, PI @SLB, MS @2*SLB, MI @3*SLB (bf16 raw logits,
// bias folded into modern side), WBg @WBOFF, biasT @BTOFF.
// slice element (v, row) at ((v>>2)*NR + row)*4 + (v&3)

typedef float  f4 __attribute__((ext_vector_type(4)));
typedef short  s8 __attribute__((ext_vector_type(8)));

__device__ __forceinline__ ushort f2bf(float f) {            // RNE f32 -> bf16
    uint u = __float_as_uint(f);
    u += 0x7fff + ((u >> 16) & 1);
    return (ushort)(u >> 16);
}
__device__ __forceinline__ float bflo(uint w) { return __uint_as_float(w << 16); }
__device__ __forceinline__ float bfhi(uint w) { return __uint_as_float(w & 0xffff0000u); }

// ---- p0: W -> fragment-ordered bf16 + bias table (unscaled, R4 numerics) ----
__global__ void p0_kernel(const float* __restrict__ Wsub, const float* __restrict__ Wins,
                          const float* __restrict__ bsub, const float* __restrict__ bins,
                          ushort* __restrict__ WBg, float* __restrict__ biasT)
{
    const int F  = blockIdx.x * 64 + threadIdx.x;   // fragment slot 0..3583
    const int l  = F & 63, s = (F >> 6) & 7, nt = F >> 9;
    const int o  = nt * 16 + (l & 15);
    const int d0 = 32 * s + 8 * (l >> 4);
    const float* w = nullptr;
    if (o < NV)       w = Wsub + o * D + d0;
    else if (o < 106) w = Wins + (o - NV) * D + d0;
    s8 bfr;
    if (w) {
        #pragma unroll
        for (int j = 0; j < 8; ++j) bfr[j] = (short)f2bf(w[j]);
    } else {
        #pragma unroll
        for (int j = 0; j < 8; ++j) bfr[j] = 0;
    }
    *(s8*)&WBg[F * 8] = bfr;
    if (F < 112) {
        float bv = 0.f;
        if (F < NV)       bv = bsub[F];
        else if (F < 106) bv = bins[F - NV];
        biasT[F] = bv;
    }
}

// ---- p1: MFMA GEMM, LDS-resident W (coalesced stage from WBg), split-K x2 ----
// block = 256 thr = 4 waves: (tile A, k0), (tile A, k1), (tile B, k0), (tile B, k1)
// grid 512 -> 1024 tiles, 2048 waves (2/SIMD), 2 blocks/CU (57 KB LDS)
__global__ __launch_bounds__(256) void p1_kernel(
    const float* __restrict__ prior, const float* __restrict__ modern,
    const ushort* __restrict__ WBg, const float* __restrict__ biasT,
    ushort* __restrict__ wsb)
{
    __shared__ ushort WB[3584 * 8];        // 57344 B; reused as f32 scratch after MFMA
    const int tid = threadIdx.x;

    #pragma unroll
    for (int i = 0; i < 14; ++i) {
        const int idx = i * 256 + tid;
        *(s8*)&WB[idx * 8] = *(const s8*)&WBg[idx * 8];
    }
    __syncthreads();

    const int wave = tid >> 6, lane = tid & 63;
    const int kh   = wave & 1;             // K-half
    const int tsub = wave >> 1;            // tile within block
    const int tile = blockIdx.x * 2 + tsub;          // 0..1023
    const int side = tile >> 9;                      // 0: prior, 1: modern
    const int row0 = (tile & 511) << 4;
    const int lrow = lane & 15, lk = lane >> 4;
    const float* __restrict__ src =
        (side ? modern : prior) + (size_t)(row0 + lrow) * D + kh * 128 + lk * 8;

    f4 acc[7];
    #pragma unroll
    for (int nt = 0; nt < 7; ++nt) { acc[nt][0]=0.f; acc[nt][1]=0.f; acc[nt][2]=0.f; acc[nt][3]=0.f; }

    #pragma unroll
    for (int s = 0; s < 4; ++s) {
        const int sg = kh * 4 + s;                   // global k-step 0..7
        const f4 c0 = *(const f4*)(src + 32 * s);
        const f4 c1 = *(const f4*)(src + 32 * s + 4);
        s8 a;
        a[0]=(short)f2bf(c0[0]); a[1]=(short)f2bf(c0[1]);
        a[2]=(short)f2bf(c0[2]); a[3]=(short)f2bf(c0[3]);
        a[4]=(short)f2bf(c1[0]); a[5]=(short)f2bf(c1[1]);
        a[6]=(short)f2bf(c1[2]); a[7]=(short)f2bf(c1[3]);
        #pragma unroll
        for (int nt = 0; nt < 7; ++nt) {
            const s8 bfr = *(const s8*)&WB[(((nt << 3) + sg) * 64 + lane) * 8];
            acc[nt] = __builtin_amdgcn_mfma_f32_16x16x32_bf16(a, bfr, acc[nt], 0, 0, 0);
        }
    }

    __syncthreads();                        // all WB reads done -> safe to reuse as scratch
    float* __restrict__ scr = (float*)WB;   // scr[tsub][nt][lane][4] = 14336 B
    if (kh == 0) {
        #pragma unroll
        for (int nt = 4; nt < 7; ++nt)
            *(f4*)&scr[((tsub * 7 + nt) * 64 + lane) * 4] = acc[nt];
    } else {
        #pragma unroll
        for (int nt = 0; nt < 4; ++nt)
            *(f4*)&scr[((tsub * 7 + nt) * 64 + lane) * 4] = acc[nt];
    }
    __syncthreads();

    // combine partner's partial, then epilogue on my nt range (R4 layout/numerics)
    const int ntlo = kh ? 4 : 0;
    const int nthi = kh ? 7 : 4;
    for (int nt = ntlo; nt < nthi; ++nt) {
        const f4 part = *(const f4*)&scr[((tsub * 7 + nt) * 64 + lane) * 4];
        const f4 full = acc[nt] + part;
        const int v = nt * 16 + lrow;
        if (v < 106) {
            const bool isS = v < NV;
            const float bias = side ? biasT[v] : 0.f;
            const int  vi  = isS ? v : v - NV;
            ushort* __restrict__ sl = wsb + (size_t)(side * 2 + (isS ? 0 : 1)) * SLB;
            const int a0 = (vi >> 2) * (NR * 4) + (vi & 3);
            #pragma unroll
            for (int r = 0; r < 4; ++r) {
                const int row = row0 + 4 * lk + r;
                sl[a0 + row * 4] = f2bf(full[r] + bias);
            }
        }
    }
}

// ---- p2: verbatim R4 — l = P[x]+M[y], lse over 53, 4 x's/thread, M reg-cached ----
__global__ __launch_bounds__(256) void p2_kernel(
    const ushort* __restrict__ wsb,
    const int* __restrict__ target, const int* __restrict__ srclen,
    const int* __restrict__ tgtlen, float* __restrict__ out)
{
    const int tid = threadIdx.x;
    const int b   = tid & 127;
    const int bid = blockIdx.x;
    const int xt  = ((bid & 7) << 1) | ((bid >> 3) & 1);   // 0..15 (XCD spread)
    const int y   = ((bid >> 4) << 1) | (tid >> 7);        // 0..63
    const int yb  = y * NB + b;

    const int sl = srclen[b], tl = tgtlen[b];
    const bool ymask = y < tl;
    const bool hasT  = y < 63;
    const int  t     = hasT ? target[y * NB + b] : 0;
    const int  toff  = (t >> 2) * (NR * 4) + (t & 3);

    float m[56], l[56];

    #pragma unroll
    for (int dist = 0; dist < 2; ++dist) {                 // 0: sub, 1: ins
        const ushort* __restrict__ P = wsb + dist * SLB;
        const ushort* __restrict__ M = wsb + (2 + dist) * SLB;

        #pragma unroll
        for (int g = 0; g < V4; ++g) {
            const uint2 q = *(const uint2*)(M + (g * NR + yb) * 4);
            m[4*g+0] = bflo(q.x); m[4*g+1] = bfhi(q.x);
            m[4*g+2] = bflo(q.y); m[4*g+3] = bfhi(q.y);
        }
        const float mlt = bflo((uint)M[toff + yb * 4]);

        float* __restrict__ o0 = out + dist * 524288;              // del / end
        float* __restrict__ o1 = out + 1048576 + dist * 516096;    // sub_probs / ins_probs

        #pragma unroll
        for (int xi = 0; xi < 4; ++xi) {
            const int x  = (xt << 2) + xi;
            const int xb = x * NB + b;
            const bool msk = (x < sl) & ymask;
            #pragma unroll
            for (int g = 0; g < V4; ++g) {
                const uint2 q = *(const uint2*)(P + (g * NR + xb) * 4);
                l[4*g+0] = bflo(q.x) + m[4*g+0];
                l[4*g+1] = bfhi(q.x) + m[4*g+1];
                l[4*g+2] = bflo(q.y) + m[4*g+2];
                l[4*g+3] = bfhi(q.y) + m[4*g+3];
            }
            float mx = l[0];
            #pragma unroll
            for (int v = 1; v < NV; ++v) mx = fmaxf(mx, l[v]);
            float ssum = 0.f;
            #pragma unroll
            for (int v = 0; v < NV; ++v) ssum += __expf(l[v] - mx);
            const float lse = mx + __logf(ssum);
            o0[((x << 6) | y) * NB + b] = msk ? (l[NV - 1] - lse) : 0.f;
            if (hasT) {
                const float lt = bflo((uint)P[toff + xb * 4]) + mlt;
                o1[(x * 63 + y) * NB + b] = msk ? (lt - lse) : 0.f;
            }
        }
    }
}

extern "C" void kernel_launch(void* const* d_in, const int* in_sizes, int n_in,
                              void* d_out, int out_size, void* d_ws, size_t ws_size,
                              hipStream_t stream) {
    const float* prior  = (const float*)d_in[0];
    const float* modern = (const float*)d_in[1];
    const float* Wsub   = (const float*)d_in[2];
    const float* bsub   = (const float*)d_in[3];
    const float* Wins   = (const float*)d_in[4];
    const float* bins   = (const float*)d_in[5];
    const int*   target = (const int*)d_in[6];
    const int*   srclen = (const int*)d_in[7];
    const int*   tgtlen = (const int*)d_in[8];
    ushort* wsb   = (ushort*)d_ws;
    ushort* WBg   = wsb + WBOFF;
    float*  biasT = (float*)(wsb + BTOFF);
    float*  out   = (float*)d_out;

    p0_kernel<<<56, 64, 0, stream>>>(Wsub, Wins, bsub, bins, WBg, biasT);
    // p1: 512 blocks x (2 tiles x 2 K-halves) -> 1024 tiles, 2048 waves
    p1_kernel<<<512, 256, 0, stream>>>(prior, modern, WBg, biasT, wsb);
    // p2: verbatim R4
    p2_kernel<<<512, 256, 0, stream>>>(wsb, target, srclen, tgtlen, out);
}

// Round 9
// 38.351 us; speedup vs baseline: 1.1100x; 1.0229x over previous
//
#include <hip/hip_runtime.h>

#define D   256
#define NB  128
#define NV  53
#define NR  8192            // rows per side (64*128)
#define V4  14              // v-groups of 4 (56 slots)
#define SLB (V4*NR*4)       // 458752 ushorts per slice
#define ESOFF (4*SLB)       // E (exp2) slices start here
#define WBOFF (8*SLB)       // fragment-ordered W (3584*8 ushorts)
#define BTOFF (WBOFF + 3584*8)  // bias table (112 floats)
#define A52   (13*NR*4)     // slice offset of v-slot 52 (group 13, sub 0)
#define LOG2E 1.44269504088896340736f
#define LN2   0.69314718055994530942f

// ws (ushort units): raw slices PS@0 PI@SLB MS@2SLB MI@3SLB (bf16 of logit*log2e,
// bias folded into modern side); E slices = exp2(raw) at +ESOFF, same layout,
// pad slots 53..55 zeroed; WBg @WBOFF; biasT @BTOFF.
// slice element (v, row) at ((v>>2)*NR + row)*4 + (v&3)

typedef float  f4 __attribute__((ext_vector_type(4)));
typedef float  f2 __attribute__((ext_vector_type(2)));
typedef short  s8 __attribute__((ext_vector_type(8)));

__device__ __forceinline__ ushort f2bf(float f) {            // RNE f32 -> bf16
    uint u = __float_as_uint(f);
    u += 0x7fff + ((u >> 16) & 1);
    return (ushort)(u >> 16);
}
__device__ __forceinline__ float bflo(uint w) { return __uint_as_float(w << 16); }
__device__ __forceinline__ float bfhi(uint w) { return __uint_as_float(w & 0xffff0000u); }
__device__ __forceinline__ float fexp2(float x) { return __builtin_exp2f(x); }
__device__ __forceinline__ float flog2(float x) { return __builtin_log2f(x); }

// ---- p0: W -> fragment-ordered bf16 (scaled by log2e) + scaled bias table ----
__global__ void p0_kernel(const float* __restrict__ Wsub, const float* __restrict__ Wins,
                          const float* __restrict__ bsub, const float* __restrict__ bins,
                          ushort* __restrict__ WBg, float* __restrict__ biasT)
{
    const int F  = blockIdx.x * 64 + threadIdx.x;   // fragment slot 0..3583
    const int l  = F & 63, s = (F >> 6) & 7, nt = F >> 9;
    const int o  = nt * 16 + (l & 15);
    const int d0 = 32 * s + 8 * (l >> 4);
    const float* w = nullptr;
    if (o < NV)       w = Wsub + o * D + d0;
    else if (o < 106) w = Wins + (o - NV) * D + d0;
    s8 bfr;
    if (w) {
        #pragma unroll
        for (int j = 0; j < 8; ++j) bfr[j] = (short)f2bf(w[j] * LOG2E);
    } else {
        #pragma unroll
        for (int j = 0; j < 8; ++j) bfr[j] = 0;
    }
    *(s8*)&WBg[F * 8] = bfr;
    if (F < 112) {
        float bv = 0.f;
        if (F < NV)       bv = bsub[F] * LOG2E;
        else if (F < 106) bv = bins[F - NV] * LOG2E;
        biasT[F] = bv;
    }
}

// ---- p1: R4 MFMA loop + coalesced LDS-W stage + full ctx preload + E epilogue ----
// grid 256 x 256thr: 4 waves/block, 1 tile(16 rows)/wave, 1024 tiles total.
__global__ __launch_bounds__(256) void p1_kernel(
    const float* __restrict__ prior, const float* __restrict__ modern,
    const ushort* __restrict__ WBg, const float* __restrict__ biasT,
    ushort* __restrict__ wsb)
{
    __shared__ ushort WB[3584 * 8];        // 57344 B
    const int tid = threadIdx.x;

    #pragma unroll
    for (int i = 0; i < 14; ++i) {         // fully coalesced 16 B copies
        const int idx = i * 256 + tid;
        *(s8*)&WB[idx * 8] = *(const s8*)&WBg[idx * 8];
    }
    __syncthreads();

    const int wave = tid >> 6, lane = tid & 63;
    const int tile = blockIdx.x * 4 + wave;           // 0..1023
    const int side = tile >> 9;                       // 0: prior, 1: modern
    const int row0 = (tile & 511) << 4;
    const int lrow = lane & 15, lk = lane >> 4;
    const float* __restrict__ src =
        (side ? modern : prior) + (size_t)(row0 + lrow) * D + lk * 8;

    // hoist ALL ctx loads (16 outstanding) so 1-wave/SIMD stalls are hidden by ILP
    f4 c[16];
    #pragma unroll
    for (int s = 0; s < 8; ++s) {
        c[2*s]   = *(const f4*)(src + 32 * s);
        c[2*s+1] = *(const f4*)(src + 32 * s + 4);
    }

    f4 acc[7];
    #pragma unroll
    for (int nt = 0; nt < 7; ++nt) { acc[nt][0]=0.f; acc[nt][1]=0.f; acc[nt][2]=0.f; acc[nt][3]=0.f; }

    #pragma unroll
    for (int s = 0; s < 8; ++s) {
        s8 a;
        a[0]=(short)f2bf(c[2*s][0]); a[1]=(short)f2bf(c[2*s][1]);
        a[2]=(short)f2bf(c[2*s][2]); a[3]=(short)f2bf(c[2*s][3]);
        a[4]=(short)f2bf(c[2*s+1][0]); a[5]=(short)f2bf(c[2*s+1][1]);
        a[6]=(short)f2bf(c[2*s+1][2]); a[7]=(short)f2bf(c[2*s+1][3]);
        #pragma unroll
        for (int nt = 0; nt < 7; ++nt) {
            const s8 bfr = *(const s8*)&WB[(((nt << 3) + s) * 64 + lane) * 8];
            acc[nt] = __builtin_amdgcn_mfma_f32_16x16x32_bf16(a, bfr, acc[nt], 0, 0, 0);
        }
    }

    // epilogue: raw bf16 + E = exp2(raw) bf16 (no max pass; log2-scaled space)
    #pragma unroll
    for (int nt = 0; nt < 7; ++nt) {
        const int v = nt * 16 + lrow;
        if (v < 106) {
            const bool isS = v < NV;
            const int  vi  = isS ? v : v - NV;
            const float bias = side ? biasT[v] : 0.f;
            ushort* __restrict__ raw = wsb + (size_t)(side * 2 + (isS ? 0 : 1)) * SLB;
            ushort* __restrict__ Eb  = raw + ESOFF;
            const int a0 = (vi >> 2) * (NR * 4) + (vi & 3);
            #pragma unroll
            for (int r = 0; r < 4; ++r) {
                const int row = row0 + 4 * lk + r;
                const float val = acc[nt][r] + bias;
                raw[a0 + row * 4] = f2bf(val);
                Eb[a0 + row * 4]  = f2bf(fexp2(val));
            }
        }
    }
    // E pad slots 53..55 <- 0 (lanes lrow 10..12 are the invalid v=106..108 lanes)
    if (lrow >= 10 && lrow <= 12) {
        const int vi = 43 + lrow;                // 53..55
        const int a0 = (vi >> 2) * (NR * 4) + (vi & 3);
        #pragma unroll
        for (int r = 0; r < 4; ++r) {
            const int row = row0 + 4 * lk + r;
            wsb[ESOFF + (size_t)(side * 2 + 0) * SLB + a0 + row * 4] = 0;
            wsb[ESOFF + (size_t)(side * 2 + 1) * SLB + a0 + row * 4] = 0;
        }
    }
}

// ---- p2: S = dot(EP, EM) over 56 slots (pads 0); lse = log2 S; no exp in loop ----
__global__ __launch_bounds__(256) void p2_kernel(
    const ushort* __restrict__ wsb,
    const int* __restrict__ target, const int* __restrict__ srclen,
    const int* __restrict__ tgtlen, float* __restrict__ out)
{
    const int tid = threadIdx.x;
    const int b   = tid & 127;
    const int bid = blockIdx.x;
    const int xt  = ((bid & 7) << 1) | ((bid >> 3) & 1);   // 0..15 (XCD spread)
    const int y   = ((bid >> 4) << 1) | (tid >> 7);        // 0..63
    const int yb  = y * NB + b;

    const int sl = srclen[b], tl = tgtlen[b];
    const bool ymask = y < tl;
    const bool hasT  = y < 63;
    const int  t     = hasT ? target[y * NB + b] : 0;
    const int  toff  = (t >> 2) * (NR * 4) + (t & 3);

    #pragma unroll 1
    for (int dist = 0; dist < 2; ++dist) {                 // 0: sub, 1: ins
        const ushort* __restrict__ Praw = wsb + dist * SLB;
        const ushort* __restrict__ Mraw = wsb + (2 + dist) * SLB;
        const ushort* __restrict__ PE   = Praw + ESOFF;
        const ushort* __restrict__ ME   = Mraw + ESOFF;

        f2 em0[V4], em1[V4];
        #pragma unroll
        for (int g = 0; g < V4; ++g) {
            const uint2 q = *(const uint2*)(ME + (g * NR + yb) * 4);
            em0[g][0] = bflo(q.x); em0[g][1] = bfhi(q.x);
            em1[g][0] = bflo(q.y); em1[g][1] = bfhi(q.y);
        }
        const float mlt = bflo((uint)Mraw[toff + yb * 4]);
        const float m52 = bflo((uint)Mraw[A52  + yb * 4]);

        float* __restrict__ o0 = out + dist * 524288;              // del / end
        float* __restrict__ o1 = out + 1048576 + dist * 516096;    // sub_probs / ins_probs

        #pragma unroll
        for (int xi = 0; xi < 4; ++xi) {
            const int x  = (xt << 2) + xi;
            const int xb = x * NB + b;
            const bool msk = (x < sl) & ymask;

            f2 s0; s0[0] = 0.f; s0[1] = 0.f;
            f2 s1; s1[0] = 0.f; s1[1] = 0.f;
            #pragma unroll
            for (int g = 0; g < V4; ++g) {
                const uint2 p = *(const uint2*)(PE + (g * NR + xb) * 4);
                f2 a; a[0] = bflo(p.x); a[1] = bfhi(p.x);
                f2 c; c[0] = bflo(p.y); c[1] = bfhi(p.y);
                s0 += a * em0[g];
                s1 += c * em1[g];
            }
            const float S  = (s0[0] + s0[1]) + (s1[0] + s1[1]);
            const float ls = flog2(S);

            const float l52 = bflo((uint)Praw[A52 + xb * 4]) + m52;
            o0[((x << 6) | y) * NB + b] = msk ? (l52 - ls) * LN2 : 0.f;
            if (hasT) {
                const float lt = bflo((uint)Praw[toff + xb * 4]) + mlt;
                o1[(x * 63 + y) * NB + b] = msk ? (lt - ls) * LN2 : 0.f;
            }
        }
    }
}

extern "C" void kernel_launch(void* const* d_in, const int* in_sizes, int n_in,
                              void* d_out, int out_size, void* d_ws, size_t ws_size,
                              hipStream_t stream) {
    const float* prior  = (const float*)d_in[0];
    const float* modern = (const float*)d_in[1];
    const float* Wsub   = (const float*)d_in[2];
    const float* bsub   = (const float*)d_in[3];
    const float* Wins   = (const float*)d_in[4];
    const float* bins   = (const float*)d_in[5];
    const int*   target = (const int*)d_in[6];
    const int*   srclen = (const int*)d_in[7];
    const int*   tgtlen = (const int*)d_in[8];
    ushort* wsb   = (ushort*)d_ws;
    ushort* WBg   = wsb + WBOFF;
    float*  biasT = (float*)(wsb + BTOFF);
    float*  out   = (float*)d_out;

    p0_kernel<<<56, 64, 0, stream>>>(Wsub, Wins, bsub, bins, WBg, biasT);
    // p1: 256 blocks x 4 waves, 1 tile/wave, LDS-resident W (coalesced stage)
    p1_kernel<<<256, 256, 0, stream>>>(prior, modern, WBg, biasT, wsb);
    // p2: E-dot, 4 x's/thread, M(E) reg-cached
    p2_kernel<<<512, 256, 0, stream>>>(wsb, target, srclen, tgtlen, out);
}